// Round 10
// baseline (438.566 us; speedup 1.0000x reference)
//
#include <hip/hip_runtime.h>
#include <cmath>

// out[dst[e], :] += attr[e] * x[src[e], :], D=64, out [25000, 64] fp32.
// Round-9: 3-pass exact-CSR build with block-LOCAL LDS binning.
// Round-8 lesson: XCD-sharded buckets did NOT merge lines (WRITE 52 MB for
// 8 MB payload) -- partial-line evictions need temporally-clustered writes,
// not just XCD-affine ones. P1 clusters them in LDS and flushes each bin as
// one contiguous burst. P2 counting-sorts each coarse bucket in LDS to exact
// per-row CSR (no global scan kernel). P3 = wave-per-row gather, 4-deep MLP.

constexpr int D4    = 16;    // float4 per 64-float row
constexpr int NBSH  = 6;     // 64 rows per coarse bucket
constexpr int RPB   = 64;    // rows per bucket
constexpr int NB_LIM = 400;  // max buckets the P1 LDS supports
constexpr int P1_C  = 3072;  // edges per P1 block
constexpr int P1_K  = 19;    // LDS slots per bin  (lambda ~7.8)
constexpr int CAPB  = 3072;  // per-bucket global capacity (lambda 2558 + 8 sigma)

// ---------------- P1: coarse binning via LDS, coalesced flush ----------------
__global__ void __launch_bounds__(256) p1_bin_kernel(
    const int* __restrict__ src, const int* __restrict__ dst,
    const float* __restrict__ attr, int* __restrict__ cursor,
    int2* __restrict__ pairs, int n_edges, int nb) {
  __shared__ int2 bins[NB_LIM * P1_K];   // 60.8 KB
  __shared__ int  bcnt[NB_LIM];
  for (int i = threadIdx.x; i < nb; i += 256) bcnt[i] = 0;
  __syncthreads();

  int base = blockIdx.x * P1_C;
  for (int i = threadIdx.x; i < P1_C; i += 256) {
    int e = base + i;
    if (e >= n_edges) break;
    int d = dst[e];
    int b = d >> NBSH;
    // pack local row (6 bits) into bits 24..29 of src (src < 2^24 here)
    int2 pr = make_int2(src[e] | ((d & (RPB - 1)) << 24), __float_as_int(attr[e]));
    int p = atomicAdd(&bcnt[b], 1);
    if (p < P1_K) {
      bins[b * P1_K + p] = pr;
    } else {  // rare LDS overflow: spill straight to global bucket
      int g = atomicAdd(&cursor[b], 1);
      if (g < CAPB) pairs[(size_t)b * CAPB + g] = pr;
    }
  }
  __syncthreads();

  // flush: wave w handles bins w, w+4, ... each bin is one contiguous burst
  int wv = threadIdx.x >> 6, ln = threadIdx.x & 63;
  for (int b = wv; b < nb; b += 4) {
    int c = min(bcnt[b], P1_K);
    int gbase = 0;
    if (ln == 0 && c > 0) gbase = atomicAdd(&cursor[b], c);
    gbase = __shfl(gbase, 0, 64);
    if (ln < c) {
      int g = gbase + ln;
      if (g < CAPB) pairs[(size_t)b * CAPB + g] = bins[b * P1_K + ln];
    }
  }
}

// ---------------- P2: per-bucket LDS counting sort -> exact CSR ----------------
__global__ void __launch_bounds__(512) p2_sort_kernel(
    const int* __restrict__ cursor, int2* __restrict__ pairs,
    int* __restrict__ row_off, int* __restrict__ row_cnt, int n_rows) {
  __shared__ int2 raw[CAPB];   // 24 KB
  __shared__ int2 srt[CAPB];   // 24 KB
  __shared__ int  cnt[RPB], off[RPB], cur[RPB];

  int b = blockIdx.x;
  int n = min(cursor[b], CAPB);
  size_t gbase = (size_t)b * CAPB;

  if (threadIdx.x < RPB) { cnt[threadIdx.x] = 0; cur[threadIdx.x] = 0; }
  __syncthreads();

  for (int i = threadIdx.x; i < n; i += 512) {
    int2 pr = pairs[gbase + i];
    raw[i] = pr;
    atomicAdd(&cnt[(pr.x >> 24) & (RPB - 1)], 1);
  }
  __syncthreads();

  if (threadIdx.x == 0) {
    int run = 0;
    for (int r = 0; r < RPB; ++r) { off[r] = run; run += cnt[r]; }
  }
  __syncthreads();

  for (int i = threadIdx.x; i < n; i += 512) {
    int2 pr = raw[i];
    int r = (pr.x >> 24) & (RPB - 1);
    int p = off[r] + atomicAdd(&cur[r], 1);
    srt[p] = make_int2(pr.x & 0xFFFFFF, pr.y);   // strip packed row
  }
  __syncthreads();

  for (int i = threadIdx.x; i < n; i += 512)
    pairs[gbase + i] = srt[i];

  if (threadIdx.x < RPB) {
    int row = b * RPB + threadIdx.x;
    if (row < n_rows) {
      row_off[row] = (int)gbase + off[threadIdx.x];
      row_cnt[row] = cnt[threadIdx.x];
    }
  }
}

// ---------------- P3: wave-per-row gather, 4-deep MLP ----------------
__global__ void __launch_bounds__(256) p3_gather_kernel(
    const float4* __restrict__ x4, const int* __restrict__ row_off,
    const int* __restrict__ row_cnt, const int2* __restrict__ pairs,
    float4* __restrict__ out4, int n_rows) {
  int wid = (blockIdx.x * blockDim.x + threadIdx.x) >> 6;
  if (wid >= n_rows) return;
  int lane = threadIdx.x & 63;
  int sub = lane >> 4;   // 0..3: edge slot
  int q   = lane & 15;   // float4 slot within row

  const int2* pb = pairs + row_off[wid];
  int n = row_cnt[wid];

  float4 a0 = make_float4(0.f,0.f,0.f,0.f), a1 = a0, a2 = a0, a3 = a0;
  int i = sub;
  for (; i + 12 < n; i += 16) {
    int2 p0 = pb[i];      int2 p1 = pb[i + 4];
    int2 p2 = pb[i + 8];  int2 p3 = pb[i + 12];
    float4 v0 = x4[(size_t)p0.x * D4 + q];
    float4 v1 = x4[(size_t)p1.x * D4 + q];
    float4 v2 = x4[(size_t)p2.x * D4 + q];
    float4 v3 = x4[(size_t)p3.x * D4 + q];
    float w0 = __int_as_float(p0.y), w1 = __int_as_float(p1.y);
    float w2 = __int_as_float(p2.y), w3 = __int_as_float(p3.y);
    a0.x += w0*v0.x; a0.y += w0*v0.y; a0.z += w0*v0.z; a0.w += w0*v0.w;
    a1.x += w1*v1.x; a1.y += w1*v1.y; a1.z += w1*v1.z; a1.w += w1*v1.w;
    a2.x += w2*v2.x; a2.y += w2*v2.y; a2.z += w2*v2.z; a2.w += w2*v2.w;
    a3.x += w3*v3.x; a3.y += w3*v3.y; a3.z += w3*v3.z; a3.w += w3*v3.w;
  }
  for (; i < n; i += 4) {
    int2 p0 = pb[i];
    float4 v0 = x4[(size_t)p0.x * D4 + q];
    float w0 = __int_as_float(p0.y);
    a0.x += w0*v0.x; a0.y += w0*v0.y; a0.z += w0*v0.z; a0.w += w0*v0.w;
  }
  a0.x += a1.x + a2.x + a3.x;
  a0.y += a1.y + a2.y + a3.y;
  a0.z += a1.z + a2.z + a3.z;
  a0.w += a1.w + a2.w + a3.w;
  for (int d = 16; d < 64; d <<= 1) {
    a0.x += __shfl_xor(a0.x, d, 64);
    a0.y += __shfl_xor(a0.y, d, 64);
    a0.z += __shfl_xor(a0.z, d, 64);
    a0.w += __shfl_xor(a0.w, d, 64);
  }
  if (sub == 0) out4[(size_t)wid * D4 + q] = a0;
}

// ---------------- fallback: round-4 capacity path ----------------
__global__ void __launch_bounds__(256) scatter_cap_kernel(
    const int* __restrict__ src, const int* __restrict__ dst,
    const float* __restrict__ attr, int* __restrict__ cursor,
    int2* __restrict__ pairs, int n_edges, int cap) {
  int e = blockIdx.x * blockDim.x + threadIdx.x;
  if (e >= n_edges) return;
  int d = dst[e];
  int p = atomicAdd(&cursor[d], 1);
  if (p < cap) pairs[(size_t)d * cap + p] = make_int2(src[e], __float_as_int(attr[e]));
}

__global__ void __launch_bounds__(256) gather_cap_kernel(
    const float4* __restrict__ x4, const int* __restrict__ cnt,
    const int2* __restrict__ pairs, float4* __restrict__ out4,
    int n_rows, int cap) {
  int wid = (blockIdx.x * blockDim.x + threadIdx.x) >> 6;
  if (wid >= n_rows) return;
  int lane = threadIdx.x & 63;
  int sub = lane >> 4, q = lane & 15;
  int n = min(cnt[wid], cap);
  const int2* pb = pairs + (size_t)wid * cap;
  float4 a0 = make_float4(0.f,0.f,0.f,0.f), a1 = a0;
  int i = sub;
  for (; i + 4 < n; i += 8) {
    int2 p0 = pb[i]; int2 p1 = pb[i + 4];
    float4 v0 = x4[(size_t)p0.x * D4 + q];
    float4 v1 = x4[(size_t)p1.x * D4 + q];
    float w0 = __int_as_float(p0.y), w1 = __int_as_float(p1.y);
    a0.x += w0*v0.x; a0.y += w0*v0.y; a0.z += w0*v0.z; a0.w += w0*v0.w;
    a1.x += w1*v1.x; a1.y += w1*v1.y; a1.z += w1*v1.z; a1.w += w1*v1.w;
  }
  if (i < n) {
    int2 p0 = pb[i];
    float4 v0 = x4[(size_t)p0.x * D4 + q];
    float w0 = __int_as_float(p0.y);
    a0.x += w0*v0.x; a0.y += w0*v0.y; a0.z += w0*v0.z; a0.w += w0*v0.w;
  }
  a0.x += a1.x; a0.y += a1.y; a0.z += a1.z; a0.w += a1.w;
  for (int d = 16; d < 64; d <<= 1) {
    a0.x += __shfl_xor(a0.x, d, 64);
    a0.y += __shfl_xor(a0.y, d, 64);
    a0.z += __shfl_xor(a0.z, d, 64);
    a0.w += __shfl_xor(a0.w, d, 64);
  }
  if (sub == 0) out4[(size_t)wid * D4 + q] = a0;
}

// ---------------- last-resort atomic fallback ----------------
__global__ void __launch_bounds__(256) scatter_add_kernel(
    const float4* __restrict__ x4, const int* __restrict__ src,
    const int* __restrict__ dst, const float* __restrict__ attr,
    float* __restrict__ out, int n_edges) {
  int t = blockIdx.x * blockDim.x + threadIdx.x;
  int e = t >> 4;
  if (e >= n_edges) return;
  int q = t & 15;
  float w = attr[e];
  float4 xv = x4[(size_t)src[e] * 16 + q];
  float* o = out + (size_t)dst[e] * 64 + q * 4;
  atomicAdd(o + 0, w * xv.x);
  atomicAdd(o + 1, w * xv.y);
  atomicAdd(o + 2, w * xv.z);
  atomicAdd(o + 3, w * xv.w);
}

// ---------------- launcher ----------------
static inline size_t align16(size_t v) { return (v + 15) & ~(size_t)15; }

extern "C" void kernel_launch(void* const* d_in, const int* in_sizes, int n_in,
                              void* d_out, int out_size, void* d_ws, size_t ws_size,
                              hipStream_t stream) {
  const float* x    = (const float*)d_in[0];
  const int*   ei   = (const int*)d_in[1];
  const float* attr = (const float*)d_in[2];
  float* out = (float*)d_out;

  const int n_edges = in_sizes[2];       // 1,000,000
  const int n_rows  = out_size / 64;     // 25,000
  const int* src = ei;
  const int* dst = ei + n_edges;

  const int nb = (n_rows + RPB - 1) >> NBSH;
  double lam = (double)n_edges / (nb > 0 ? nb : 1);
  bool shape_ok = (nb > 0) && (nb <= NB_LIM) &&
                  (lam + 8.0 * sqrt(lam) + 64.0 <= (double)CAPB);

  size_t cur_b  = align16((size_t)nb * 4);
  size_t roff_b = align16((size_t)n_rows * 4);
  size_t rcnt_b = align16((size_t)n_rows * 4);
  size_t need = cur_b + roff_b + rcnt_b + (size_t)nb * CAPB * 8;

  if (shape_ok && ws_size >= need) {
    int*  cursor  = (int*)d_ws;
    int*  row_off = (int*)((char*)d_ws + cur_b);
    int*  row_cnt = (int*)((char*)d_ws + cur_b + roff_b);
    int2* pairs   = (int2*)((char*)d_ws + cur_b + roff_b + rcnt_b);

    hipMemsetAsync(cursor, 0, (size_t)nb * 4, stream);

    int p1_grid = (n_edges + P1_C - 1) / P1_C;
    p1_bin_kernel<<<p1_grid, 256, 0, stream>>>(src, dst, attr, cursor, pairs,
                                               n_edges, nb);
    p2_sort_kernel<<<nb, 512, 0, stream>>>(cursor, pairs, row_off, row_cnt,
                                           n_rows);
    int p3_grid = (int)(((long long)n_rows * 64 + 255) / 256);
    p3_gather_kernel<<<p3_grid, 256, 0, stream>>>(
        (const float4*)x, row_off, row_cnt, pairs, (float4*)d_out, n_rows);
    return;
  }

  // --- fallback: round-4 capacity path ---
  const int eb = (n_edges + 255) / 256;
  const int gb = (int)(((long long)n_rows * 64 + 255) / 256);
  size_t cb = align16((size_t)n_rows * 4);
  for (int cap : {128, 96}) {
    size_t need2 = cb + (size_t)n_rows * cap * 8;
    if (ws_size >= need2) {
      int* cursor = (int*)d_ws;
      int2* pairs = (int2*)((char*)d_ws + cb);
      hipMemsetAsync(cursor, 0, (size_t)n_rows * 4, stream);
      scatter_cap_kernel<<<eb, 256, 0, stream>>>(src, dst, attr, cursor, pairs,
                                                 n_edges, cap);
      gather_cap_kernel<<<gb, 256, 0, stream>>>(
          (const float4*)x, cursor, pairs, (float4*)d_out, n_rows, cap);
      return;
    }
  }

  // --- atomic last resort ---
  hipMemsetAsync(d_out, 0, (size_t)out_size * sizeof(float), stream);
  long long threads = (long long)n_edges * 16;
  scatter_add_kernel<<<(int)((threads + 255) / 256), 256, 0, stream>>>(
      (const float4*)x, src, dst, attr, out, n_edges);
}

// Round 13
// 138.238 us; speedup vs baseline: 3.1725x; 3.1725x over previous
//
#include <hip/hip_runtime.h>
#include <cmath>

// out[dst[e], :] += attr[e] * x[src[e], :], D=64, out [25000, 64] fp32.
// Round-11: fix round-10's P1 flush serialization. Round-10 profile: P1 was
// 350 us (predicted 15) with WRITE=13.6 MB (write-amp fix CONFIRMED). Cause:
// flush loop = serial dependent chain {atomicAdd(cursor[b]) -> shfl -> store}
// x98 iters/wave, and all 326 blocks walk bins in the SAME order -> lockstep
// same-address atomic contention, ~400ns each, unhidden at 1 wave/SIMD.
// Fix: reserve cursor space for ALL bins in parallel (one atomic per bin by
// distinct threads -> gbase_s[] in LDS), then an atomic-free copy loop.
// P2: wave shfl-scan replaces thread-0 serial 64-prefix. P3 unchanged.

constexpr int D4    = 16;    // float4 per 64-float row
constexpr int NBSH  = 6;     // 64 rows per coarse bucket
constexpr int RPB   = 64;    // rows per bucket
constexpr int NB_LIM = 400;  // max buckets the P1 LDS supports
constexpr int P1_C  = 3072;  // edges per P1 block
constexpr int P1_K  = 19;    // LDS slots per bin  (lambda ~7.8)
constexpr int CAPB  = 3072;  // per-bucket global capacity (lambda 2558 + 8 sigma)

// ---------------- P1: coarse binning via LDS, parallel-reserve flush ----------------
__global__ void __launch_bounds__(256) p1_bin_kernel(
    const int* __restrict__ src, const int* __restrict__ dst,
    const float* __restrict__ attr, int* __restrict__ cursor,
    int2* __restrict__ pairs, int n_edges, int nb) {
  __shared__ int2 bins[NB_LIM * P1_K];   // 60.8 KB
  __shared__ int  bcnt[NB_LIM];          // 1.6 KB
  __shared__ int  gbase_s[NB_LIM];       // 1.6 KB  (total 64.0 KB)
  for (int i = threadIdx.x; i < nb; i += 256) bcnt[i] = 0;
  __syncthreads();

  int base = blockIdx.x * P1_C;
  for (int i = threadIdx.x; i < P1_C; i += 256) {
    int e = base + i;
    if (e >= n_edges) break;
    int d = dst[e];
    int b = d >> NBSH;
    // pack local row (6 bits) into bits 24..29 of src (src < 2^24 here)
    int2 pr = make_int2(src[e] | ((d & (RPB - 1)) << 24), __float_as_int(attr[e]));
    int p = atomicAdd(&bcnt[b], 1);
    if (p < P1_K) {
      bins[b * P1_K + p] = pr;
    } else {  // rare LDS overflow: spill straight to global bucket
      int g = atomicAdd(&cursor[b], 1);
      if (g < CAPB) pairs[(size_t)b * CAPB + g] = pr;
    }
  }
  __syncthreads();

  // parallel reservation: one global atomic per non-empty bin, all at once
  for (int b = threadIdx.x; b < nb; b += 256) {
    int c = min(bcnt[b], P1_K);
    gbase_s[b] = (c > 0) ? atomicAdd(&cursor[b], c) : 0;
  }
  __syncthreads();

  // atomic-free copy: wave w handles bins w, w+4, ...; contiguous burst per bin
  int wv = threadIdx.x >> 6, ln = threadIdx.x & 63;
  for (int b = wv; b < nb; b += 4) {
    int c = min(bcnt[b], P1_K);
    if (ln < c) {
      int g = gbase_s[b] + ln;
      if (g < CAPB) pairs[(size_t)b * CAPB + g] = bins[b * P1_K + ln];
    }
  }
}

// ---------------- P2: per-bucket LDS counting sort -> exact CSR ----------------
__global__ void __launch_bounds__(512) p2_sort_kernel(
    const int* __restrict__ cursor, int2* __restrict__ pairs,
    int* __restrict__ row_off, int* __restrict__ row_cnt, int n_rows) {
  __shared__ int2 raw[CAPB];   // 24 KB
  __shared__ int2 srt[CAPB];   // 24 KB
  __shared__ int  cnt[RPB], off[RPB], cur[RPB];

  int b = blockIdx.x;
  int n = min(cursor[b], CAPB);
  size_t gbase = (size_t)b * CAPB;

  if (threadIdx.x < RPB) { cnt[threadIdx.x] = 0; cur[threadIdx.x] = 0; }
  __syncthreads();

  for (int i = threadIdx.x; i < n; i += 512) {
    int2 pr = pairs[gbase + i];
    raw[i] = pr;
    atomicAdd(&cnt[(pr.x >> 24) & (RPB - 1)], 1);
  }
  __syncthreads();

  // wave-parallel exclusive scan over 64 counts (threads 0..63 = wave 0)
  if (threadIdx.x < RPB) {
    int c = cnt[threadIdx.x];
    int v = c;
    for (int d = 1; d < 64; d <<= 1) {
      int u = __shfl_up(v, d, 64);
      if (threadIdx.x >= d) v += u;
    }
    off[threadIdx.x] = v - c;  // exclusive prefix
  }
  __syncthreads();

  for (int i = threadIdx.x; i < n; i += 512) {
    int2 pr = raw[i];
    int r = (pr.x >> 24) & (RPB - 1);
    int p = off[r] + atomicAdd(&cur[r], 1);
    srt[p] = make_int2(pr.x & 0xFFFFFF, pr.y);   // strip packed row
  }
  __syncthreads();

  for (int i = threadIdx.x; i < n; i += 512)
    pairs[gbase + i] = srt[i];

  if (threadIdx.x < RPB) {
    int row = b * RPB + threadIdx.x;
    if (row < n_rows) {
      row_off[row] = (int)gbase + off[threadIdx.x];
      row_cnt[row] = cnt[threadIdx.x];
    }
  }
}

// ---------------- P3: wave-per-row gather, 4-deep MLP ----------------
__global__ void __launch_bounds__(256) p3_gather_kernel(
    const float4* __restrict__ x4, const int* __restrict__ row_off,
    const int* __restrict__ row_cnt, const int2* __restrict__ pairs,
    float4* __restrict__ out4, int n_rows) {
  int wid = (blockIdx.x * blockDim.x + threadIdx.x) >> 6;
  if (wid >= n_rows) return;
  int lane = threadIdx.x & 63;
  int sub = lane >> 4;   // 0..3: edge slot
  int q   = lane & 15;   // float4 slot within row

  const int2* pb = pairs + row_off[wid];
  int n = row_cnt[wid];

  float4 a0 = make_float4(0.f,0.f,0.f,0.f), a1 = a0, a2 = a0, a3 = a0;
  int i = sub;
  for (; i + 12 < n; i += 16) {
    int2 p0 = pb[i];      int2 p1 = pb[i + 4];
    int2 p2 = pb[i + 8];  int2 p3 = pb[i + 12];
    float4 v0 = x4[(size_t)p0.x * D4 + q];
    float4 v1 = x4[(size_t)p1.x * D4 + q];
    float4 v2 = x4[(size_t)p2.x * D4 + q];
    float4 v3 = x4[(size_t)p3.x * D4 + q];
    float w0 = __int_as_float(p0.y), w1 = __int_as_float(p1.y);
    float w2 = __int_as_float(p2.y), w3 = __int_as_float(p3.y);
    a0.x += w0*v0.x; a0.y += w0*v0.y; a0.z += w0*v0.z; a0.w += w0*v0.w;
    a1.x += w1*v1.x; a1.y += w1*v1.y; a1.z += w1*v1.z; a1.w += w1*v1.w;
    a2.x += w2*v2.x; a2.y += w2*v2.y; a2.z += w2*v2.z; a2.w += w2*v2.w;
    a3.x += w3*v3.x; a3.y += w3*v3.y; a3.z += w3*v3.z; a3.w += w3*v3.w;
  }
  for (; i < n; i += 4) {
    int2 p0 = pb[i];
    float4 v0 = x4[(size_t)p0.x * D4 + q];
    float w0 = __int_as_float(p0.y);
    a0.x += w0*v0.x; a0.y += w0*v0.y; a0.z += w0*v0.z; a0.w += w0*v0.w;
  }
  a0.x += a1.x + a2.x + a3.x;
  a0.y += a1.y + a2.y + a3.y;
  a0.z += a1.z + a2.z + a3.z;
  a0.w += a1.w + a2.w + a3.w;
  for (int d = 16; d < 64; d <<= 1) {
    a0.x += __shfl_xor(a0.x, d, 64);
    a0.y += __shfl_xor(a0.y, d, 64);
    a0.z += __shfl_xor(a0.z, d, 64);
    a0.w += __shfl_xor(a0.w, d, 64);
  }
  if (sub == 0) out4[(size_t)wid * D4 + q] = a0;
}

// ---------------- fallback: round-4 capacity path ----------------
__global__ void __launch_bounds__(256) scatter_cap_kernel(
    const int* __restrict__ src, const int* __restrict__ dst,
    const float* __restrict__ attr, int* __restrict__ cursor,
    int2* __restrict__ pairs, int n_edges, int cap) {
  int e = blockIdx.x * blockDim.x + threadIdx.x;
  if (e >= n_edges) return;
  int d = dst[e];
  int p = atomicAdd(&cursor[d], 1);
  if (p < cap) pairs[(size_t)d * cap + p] = make_int2(src[e], __float_as_int(attr[e]));
}

__global__ void __launch_bounds__(256) gather_cap_kernel(
    const float4* __restrict__ x4, const int* __restrict__ cnt,
    const int2* __restrict__ pairs, float4* __restrict__ out4,
    int n_rows, int cap) {
  int wid = (blockIdx.x * blockDim.x + threadIdx.x) >> 6;
  if (wid >= n_rows) return;
  int lane = threadIdx.x & 63;
  int sub = lane >> 4, q = lane & 15;
  int n = min(cnt[wid], cap);
  const int2* pb = pairs + (size_t)wid * cap;
  float4 a0 = make_float4(0.f,0.f,0.f,0.f), a1 = a0;
  int i = sub;
  for (; i + 4 < n; i += 8) {
    int2 p0 = pb[i]; int2 p1 = pb[i + 4];
    float4 v0 = x4[(size_t)p0.x * D4 + q];
    float4 v1 = x4[(size_t)p1.x * D4 + q];
    float w0 = __int_as_float(p0.y), w1 = __int_as_float(p1.y);
    a0.x += w0*v0.x; a0.y += w0*v0.y; a0.z += w0*v0.z; a0.w += w0*v0.w;
    a1.x += w1*v1.x; a1.y += w1*v1.y; a1.z += w1*v1.z; a1.w += w1*v1.w;
  }
  if (i < n) {
    int2 p0 = pb[i];
    float4 v0 = x4[(size_t)p0.x * D4 + q];
    float w0 = __int_as_float(p0.y);
    a0.x += w0*v0.x; a0.y += w0*v0.y; a0.z += w0*v0.z; a0.w += w0*v0.w;
  }
  a0.x += a1.x; a0.y += a1.y; a0.z += a1.z; a0.w += a1.w;
  for (int d = 16; d < 64; d <<= 1) {
    a0.x += __shfl_xor(a0.x, d, 64);
    a0.y += __shfl_xor(a0.y, d, 64);
    a0.z += __shfl_xor(a0.z, d, 64);
    a0.w += __shfl_xor(a0.w, d, 64);
  }
  if (sub == 0) out4[(size_t)wid * D4 + q] = a0;
}

// ---------------- last-resort atomic fallback ----------------
__global__ void __launch_bounds__(256) scatter_add_kernel(
    const float4* __restrict__ x4, const int* __restrict__ src,
    const int* __restrict__ dst, const float* __restrict__ attr,
    float* __restrict__ out, int n_edges) {
  int t = blockIdx.x * blockDim.x + threadIdx.x;
  int e = t >> 4;
  if (e >= n_edges) return;
  int q = t & 15;
  float w = attr[e];
  float4 xv = x4[(size_t)src[e] * 16 + q];
  float* o = out + (size_t)dst[e] * 64 + q * 4;
  atomicAdd(o + 0, w * xv.x);
  atomicAdd(o + 1, w * xv.y);
  atomicAdd(o + 2, w * xv.z);
  atomicAdd(o + 3, w * xv.w);
}

// ---------------- launcher ----------------
static inline size_t align16(size_t v) { return (v + 15) & ~(size_t)15; }

extern "C" void kernel_launch(void* const* d_in, const int* in_sizes, int n_in,
                              void* d_out, int out_size, void* d_ws, size_t ws_size,
                              hipStream_t stream) {
  const float* x    = (const float*)d_in[0];
  const int*   ei   = (const int*)d_in[1];
  const float* attr = (const float*)d_in[2];
  float* out = (float*)d_out;

  const int n_edges = in_sizes[2];       // 1,000,000
  const int n_rows  = out_size / 64;     // 25,000
  const int* src = ei;
  const int* dst = ei + n_edges;

  const int nb = (n_rows + RPB - 1) >> NBSH;
  double lam = (double)n_edges / (nb > 0 ? nb : 1);
  bool shape_ok = (nb > 0) && (nb <= NB_LIM) &&
                  (lam + 8.0 * sqrt(lam) + 64.0 <= (double)CAPB);

  size_t cur_b  = align16((size_t)nb * 4);
  size_t roff_b = align16((size_t)n_rows * 4);
  size_t rcnt_b = align16((size_t)n_rows * 4);
  size_t need = cur_b + roff_b + rcnt_b + (size_t)nb * CAPB * 8;

  if (shape_ok && ws_size >= need) {
    int*  cursor  = (int*)d_ws;
    int*  row_off = (int*)((char*)d_ws + cur_b);
    int*  row_cnt = (int*)((char*)d_ws + cur_b + roff_b);
    int2* pairs   = (int2*)((char*)d_ws + cur_b + roff_b + rcnt_b);

    hipMemsetAsync(cursor, 0, (size_t)nb * 4, stream);

    int p1_grid = (n_edges + P1_C - 1) / P1_C;
    p1_bin_kernel<<<p1_grid, 256, 0, stream>>>(src, dst, attr, cursor, pairs,
                                               n_edges, nb);
    p2_sort_kernel<<<nb, 512, 0, stream>>>(cursor, pairs, row_off, row_cnt,
                                           n_rows);
    int p3_grid = (int)(((long long)n_rows * 64 + 255) / 256);
    p3_gather_kernel<<<p3_grid, 256, 0, stream>>>(
        (const float4*)x, row_off, row_cnt, pairs, (float4*)d_out, n_rows);
    return;
  }

  // --- fallback: round-4 capacity path ---
  const int eb = (n_edges + 255) / 256;
  const int gb = (int)(((long long)n_rows * 64 + 255) / 256);
  size_t cb = align16((size_t)n_rows * 4);
  for (int cap : {128, 96}) {
    size_t need2 = cb + (size_t)n_rows * cap * 8;
    if (ws_size >= need2) {
      int* cursor = (int*)d_ws;
      int2* pairs = (int2*)((char*)d_ws + cb);
      hipMemsetAsync(cursor, 0, (size_t)n_rows * 4, stream);
      scatter_cap_kernel<<<eb, 256, 0, stream>>>(src, dst, attr, cursor, pairs,
                                                 n_edges, cap);
      gather_cap_kernel<<<gb, 256, 0, stream>>>(
          (const float4*)x, cursor, pairs, (float4*)d_out, n_rows, cap);
      return;
    }
  }

  // --- atomic last resort ---
  hipMemsetAsync(d_out, 0, (size_t)out_size * sizeof(float), stream);
  long long threads = (long long)n_edges * 16;
  scatter_add_kernel<<<(int)((threads + 255) / 256), 256, 0, stream>>>(
      (const float4*)x, src, dst, attr, out, n_edges);
}